// Round 21
// baseline (51.672 us; speedup 1.0000x reference)
//
#include <hip/hip_runtime.h>

#define NB 64
#define NN 4096
#define NC 128
#define NH 4
#define HC (NH * NC)        // 512
#define PSTRIDE (8 + HC)    // 520 floats per partial
#define NSLICE 64           // 64 blocks/graph -> 4096 blocks, ONE 64-row tile each
#define TROWS 64            // rows per LDS tile (32 KB)
#define LRELU 0.2f

// ---------------- k0: wt[k][h] = sum_c W[k, h*C+c] * t[h,c];  bt[h] = sum_c bias*t.
__global__ __launch_bounds__(128) void k0_wt(const float* __restrict__ W,
                                             const float* __restrict__ bias,
                                             const float* __restrict__ tune,
                                             float* __restrict__ wtbt)
{
    const int bid = blockIdx.x;
    const int t = threadIdx.x;                       // 0..127
    const float* src = (bid < NC) ? (W + (size_t)bid * HC) : bias;
    float* dst = (bid < NC) ? (wtbt + bid * NH) : (wtbt + NC * NH);
    const float4 a = reinterpret_cast<const float4*>(src)[t];
    const float4 b = reinterpret_cast<const float4*>(tune)[t];
    float p = a.x * b.x + a.y * b.y + a.z * b.z + a.w * b.w;
    #pragma unroll
    for (int off = 16; off; off >>= 1) p += __shfl_xor(p, off, 32);
    if ((t & 31) == 0) dst[t >> 5] = p;              // group t>>5 == head h
}

// ---------------- k1: 64 blocks per graph, ONE tile per block. Block (slice,b) owns
// rows [slice*segB, min(+segB, gs)), segB = ceil(gs/64) <= 64. Stage 32KB once ->
// compute once -> write partial. Empty blocks exit to zero-partial; CU slots are
// backfilled by the scheduler -> no straggler tail (r15's blocks ran up to 4 tiles
// serially while the rest of the machine idled).
__global__ __launch_bounds__(256, 4) void k1_part(const float* __restrict__ V,
                                                  const int* __restrict__ gs,
                                                  const float* __restrict__ wtbt,
                                                  float* __restrict__ part)
{
    __shared__ float smem[8192];                     // 32 KB, unioned
    float (*Vt)[NC] = reinterpret_cast<float(*)[NC]>(smem);          // [64][128]
    float (*Sall)[NH][132] = reinterpret_cast<float(*)[NH][132]>(smem); // [8][4][132]
    float* llds = smem + 8 * NH * 132;               // 32 floats

    const int slice = blockIdx.x;
    const int b = blockIdx.y;
    const int tid = threadIdx.x;
    const int hw = tid >> 5;          // half-wave 0..7
    const int lane = tid & 31;
    const int h = lane >> 3;          // head 0..3
    const int j = lane & 7;           // feature-group (features 16j..16j+15)
    const int gsz = gs[b];

    const int segB = (gsz + NSLICE - 1) / NSLICE;    // rows per block (<= 64)
    const int myBeg = slice * segB;
    int myEnd = myBeg + segB;
    if (myEnd > gsz) myEnd = gsz;
    const bool hasWork = (myEnd > myBeg);

    float l = 0.f;
    float S[16] = {};

    if (hasWork) {
        float wtk[16];
        #pragma unroll
        for (int u = 0; u < 16; ++u) wtk[u] = wtbt[(16 * j + u) * NH + h];
        const float bt = wtbt[HC + h];

        const float4* Vg4 = reinterpret_cast<const float4*>(V);
        const size_t gbase = (size_t)b * NN;

        // ---- stage once: 2048 float4; thread t does idx = t + 256k (8 indep loads)
        float4 r[8];
        #pragma unroll
        for (int k = 0; k < 8; ++k) {
            const int idx = tid + (k << 8);
            const int gr = myBeg + (idx >> 5);
            const int src_row = (gr < myEnd) ? gr : myBeg;   // clamp (masked later)
            r[k] = Vg4[(gbase + src_row) * 32 + (idx & 31)];
        }
        #pragma unroll
        for (int k = 0; k < 8; ++k) {
            const int idx = tid + (k << 8);
            reinterpret_cast<float4*>(smem)[idx] = r[k];
        }
        __syncthreads();
        // ---- compute once: half-wave hw handles rows hw*8 .. hw*8+7 from LDS
        #pragma unroll 2
        for (int rr = 0; rr < 8; ++rr) {
            const int row = (hw << 3) + rr;
            const bool valid = (myBeg + row < myEnd);
            const float4* vr = reinterpret_cast<const float4*>(&Vt[row][j * 16]);
            const float4 A0 = vr[0];
            const float4 A1 = vr[1];
            const float4 A2 = vr[2];
            const float4 A3 = vr[3];
            float a0 = A0.x * wtk[0]  + A0.y * wtk[1]  + A0.z * wtk[2]  + A0.w * wtk[3];
            float a1 = A1.x * wtk[4]  + A1.y * wtk[5]  + A1.z * wtk[6]  + A1.w * wtk[7];
            float a2 = A2.x * wtk[8]  + A2.y * wtk[9]  + A2.z * wtk[10] + A2.w * wtk[11];
            float a3 = A3.x * wtk[12] + A3.y * wtk[13] + A3.z * wtk[14] + A3.w * wtk[15];
            float lg = (a0 + a1) + (a2 + a3);
            lg += __shfl_xor(lg, 1, 32);
            lg += __shfl_xor(lg, 2, 32);
            lg += __shfl_xor(lg, 4, 32);   // 8-lane head group holds full logit
            float x = lg + bt;
            x = (x >= 0.f) ? x : LRELU * x;           // leaky_relu
            float p = __expf(x);                      // no max subtraction
            p = valid ? p : 0.f;
            l += p;
            S[0]  += p * A0.x;  S[1]  += p * A0.y;  S[2]  += p * A0.z;  S[3]  += p * A0.w;
            S[4]  += p * A1.x;  S[5]  += p * A1.y;  S[6]  += p * A1.z;  S[7]  += p * A1.w;
            S[8]  += p * A2.x;  S[9]  += p * A2.y;  S[10] += p * A2.z;  S[11] += p * A2.w;
            S[12] += p * A3.x;  S[13] += p * A3.y;  S[14] += p * A3.z;  S[15] += p * A3.w;
        }
        __syncthreads();                              // Vt free for combine reuse
    }

    // ---- block combine across 8 half-waves (smem reused: Sall/llds)
    if (j == 0) llds[hw * NH + h] = l;
    #pragma unroll
    for (int t = 0; t < 4; ++t) {
        float4 s4;
        s4.x = S[4 * t]; s4.y = S[4 * t + 1]; s4.z = S[4 * t + 2]; s4.w = S[4 * t + 3];
        *reinterpret_cast<float4*>(&Sall[hw][h][16 * j + 4 * t]) = s4;
    }
    __syncthreads();
    float* pb = part + (size_t)(b * NSLICE + slice) * PSTRIDE;
    if (tid < 4) {
        float L = 0.f;
        #pragma unroll
        for (int ww = 0; ww < 8; ++ww) L += llds[ww * NH + tid];
        pb[4 + tid] = L;
    }
    #pragma unroll
    for (int r2 = 0; r2 < 2; ++r2) {
        const int e = tid + r2 * 256;
        const int hh = e >> 7, k = e & 127;
        float s = 0.f;
        #pragma unroll
        for (int ww = 0; ww < 8; ++ww) s += Sall[ww][hh][k];
        pb[8 + e] = s;
    }
}

// ---------------- k2: block (b, h): merge 64 partials for head h (wave-parallel
// L-reduce), then out[b, h*128+d] = (S[h]/L[h]) . W[:, h*128+d] + bias[h*128+d]
__global__ __launch_bounds__(128) void k2_out(const float* __restrict__ part,
                                              const float* __restrict__ W,
                                              const float* __restrict__ bias,
                                              float* __restrict__ out)
{
    const int b = blockIdx.x;
    const int h = blockIdx.y;
    const int tid = threadIdx.x;     // 0..127
    const float* pb = part + (size_t)b * NSLICE * PSTRIDE;

    __shared__ float Sn[NC];
    __shared__ float sL;
    if (tid < 64) {                   // one full wave: parallel L loads + reduce
        float lv = pb[(size_t)tid * PSTRIDE + 4 + h];
        #pragma unroll
        for (int off = 32; off; off >>= 1) lv += __shfl_down(lv, off, 64);
        if (tid == 0) sL = lv;
    }
    __syncthreads();
    {
        float s = 0.f;
        #pragma unroll 8
        for (int c = 0; c < NSLICE; ++c)
            s += pb[(size_t)c * PSTRIDE + 8 + h * NC + tid];
        Sn[tid] = s / sL;
    }
    __syncthreads();
    const int d = h * NC + tid;
    float acc = 0.f;
    #pragma unroll 4
    for (int k = 0; k < NC; ++k) acc += Sn[k] * W[(size_t)k * HC + d];
    out[(size_t)b * HC + d] = acc + bias[d];
}

extern "C" void kernel_launch(void* const* d_in, const int* in_sizes, int n_in,
                              void* d_out, int out_size, void* d_ws, size_t ws_size,
                              hipStream_t stream)
{
    const float* V    = (const float*)d_in[0];
    const int*   gsz  = (const int*)d_in[1];
    const float* W    = (const float*)d_in[2];
    const float* bias = (const float*)d_in[3];
    const float* tune = (const float*)d_in[4];
    float* out  = (float*)d_out;
    float* wtbt = (float*)d_ws;            // 520 floats (516 used)
    float* part = wtbt + PSTRIDE;          // NB*NSLICE*PSTRIDE floats (~8.5 MB)

    hipLaunchKernelGGL(k0_wt, dim3(NC + 1), dim3(128), 0, stream, W, bias, tune, wtbt);
    hipLaunchKernelGGL(k1_part, dim3(NSLICE, NB), dim3(256), 0, stream, V, gsz, wtbt, part);
    hipLaunchKernelGGL(k2_out, dim3(NB, NH), dim3(128), 0, stream, part, W, bias, out);
}

// Round 22
// 47.582 us; speedup vs baseline: 1.0860x; 1.0860x over previous
//
#include <hip/hip_runtime.h>

#define NB 64
#define NN 4096
#define NC 128
#define NH 4
#define HC (NH * NC)        // 512
#define PSTRIDE (8 + HC)    // 520 floats per partial
#define NSLICE 16           // 16*64 = 1024 blocks
#define LRELU 0.2f

// ---------------- k0: wt[k][h] = sum_c W[k, h*C+c] * t[h,c];  bt[h] = sum_c bias*t.
__global__ __launch_bounds__(128) void k0_wt(const float* __restrict__ W,
                                             const float* __restrict__ bias,
                                             const float* __restrict__ tune,
                                             float* __restrict__ wtbt)
{
    const int bid = blockIdx.x;
    const int t = threadIdx.x;                       // 0..127
    const float* src = (bid < NC) ? (W + (size_t)bid * HC) : bias;
    float* dst = (bid < NC) ? (wtbt + bid * NH) : (wtbt + NC * NH);
    const float4 a = reinterpret_cast<const float4*>(src)[t];
    const float4 b = reinterpret_cast<const float4*>(tune)[t];
    float p = a.x * b.x + a.y * b.y + a.z * b.z + a.w * b.w;
    #pragma unroll
    for (int off = 16; off; off >>= 1) p += __shfl_xor(p, off, 32);
    if ((t & 31) == 0) dst[t >> 5] = p;              // group t>>5 == head h
}

// ---------------- k1: ONE WAVE PER ROW, 6-deep explicit pipeline.
// Block (slice,b) owns contiguous rows [slice*segB, min(+segB,gs)); wave wv (0..3)
// handles rows myBeg+wv+4*i. Lane = h*16+j: head h, features [8j,8j+8).
// Per-lane state: S[8]+wtk[8] (half of r15) -> room for 6 slots x 2 float4 in
// flight (48 VGPR). Each body computes slot k then re-issues its load for row+6:
// ~6 outstanding loads/lane, no LDS/barriers in the hot loop.
// Logit reduce = 4-step xor butterfly within the 16-lane head group.
__global__ __launch_bounds__(256, 4) void k1_part(const float* __restrict__ V,
                                                  const int* __restrict__ gs,
                                                  const float* __restrict__ wtbt,
                                                  float* __restrict__ part)
{
    const int slice = blockIdx.x;
    const int b = blockIdx.y;
    const int tid = threadIdx.x;
    const int wv = tid >> 6;          // wave 0..3
    const int lane = tid & 63;
    const int h = lane >> 4;          // head 0..3
    const int j = lane & 15;          // feature-group: features [8j, 8j+8)
    const int gsz = gs[b];

    float wtk[8];
    #pragma unroll
    for (int u = 0; u < 8; ++u) wtk[u] = wtbt[(8 * j + u) * NH + h];
    const float bt = wtbt[HC + h];

    const int segB = (gsz + NSLICE - 1) / NSLICE;    // rows per block
    const int myBeg = slice * segB;
    int myEnd = myBeg + segB;
    if (myEnd > gsz) myEnd = gsz;
    const int rem = myEnd - myBeg - wv;
    const int iters = rem > 0 ? ((rem + 3) >> 2) : 0;   // rows wv+4*i of segment

    float l = 0.f;
    float S[8] = {};

    const float* base = V + ((size_t)b * NN + myBeg + wv) * NC + j * 8;
    const size_t RST = (size_t)4 * NC;               // wave's row stride (floats)

    if (iters > 0) {
        float4 a0, a1, b0, b1, c0, c1, d0, d1, e0, e1, f0, f1;

#define LD2(D0, D1, ROW) { int nr_ = (ROW); nr_ = (nr_ < iters) ? nr_ : 0;            \
        const float4* p_ = reinterpret_cast<const float4*>(base + (size_t)nr_ * RST); \
        D0 = p_[0]; D1 = p_[1]; }

        LD2(a0, a1, 0) LD2(b0, b1, 1) LD2(c0, c1, 2)
        LD2(d0, d1, 3) LD2(e0, e1, 4) LD2(f0, f1, 5)

#define BODY(V0, V1, K) {                                                             \
        const int row_ = i + (K);                                                     \
        float pd = V0.x * wtk[0] + V0.y * wtk[1] + V0.z * wtk[2] + V0.w * wtk[3]      \
                 + V1.x * wtk[4] + V1.y * wtk[5] + V1.z * wtk[6] + V1.w * wtk[7];     \
        pd += __shfl_xor(pd, 1, 64);                                                  \
        pd += __shfl_xor(pd, 2, 64);                                                  \
        pd += __shfl_xor(pd, 4, 64);                                                  \
        pd += __shfl_xor(pd, 8, 64);   /* 16-lane head group holds full logit */      \
        float x_ = pd + bt;                                                           \
        x_ = (x_ >= 0.f) ? x_ : LRELU * x_;          /* leaky_relu */                 \
        float p_ = __expf(x_);                       /* no max subtraction */         \
        p_ = (row_ < iters) ? p_ : 0.f;                                               \
        l += p_;                                                                      \
        S[0] += p_ * V0.x; S[1] += p_ * V0.y; S[2] += p_ * V0.z; S[3] += p_ * V0.w;   \
        S[4] += p_ * V1.x; S[5] += p_ * V1.y; S[6] += p_ * V1.z; S[7] += p_ * V1.w;   \
        LD2(V0, V1, row_ + 6)                        /* refill slot, 6 deep */        \
    }

        for (int i = 0; i < iters; i += 6) {
            BODY(a0, a1, 0)
            BODY(b0, b1, 1)
            BODY(c0, c1, 2)
            BODY(d0, d1, 3)
            BODY(e0, e1, 4)
            BODY(f0, f1, 5)
        }
#undef BODY
#undef LD2
    }

    // ---- block combine across 4 waves
    __shared__ float llds[4][4];
    __shared__ float Sall[4][4][132];    // padded
    if (j == 0) llds[wv][h] = l;
    *reinterpret_cast<float4*>(&Sall[wv][h][8 * j])     = make_float4(S[0], S[1], S[2], S[3]);
    *reinterpret_cast<float4*>(&Sall[wv][h][8 * j + 4]) = make_float4(S[4], S[5], S[6], S[7]);
    __syncthreads();
    float* pb = part + (size_t)(b * NSLICE + slice) * PSTRIDE;
    if (tid < 4) {
        float L = 0.f;
        #pragma unroll
        for (int w2 = 0; w2 < 4; ++w2) L += llds[w2][tid];
        pb[4 + tid] = L;
    }
    #pragma unroll
    for (int r2 = 0; r2 < 2; ++r2) {
        const int e = tid + r2 * 256;
        const int hh = e >> 7, k = e & 127;
        float s = 0.f;
        #pragma unroll
        for (int w2 = 0; w2 < 4; ++w2) s += Sall[w2][hh][k];
        pb[8 + e] = s;
    }
}

// ---------------- k2: block (b, h): merge NSLICE partials for head h, then
// out[b, h*128+d] = (S[h]/L[h]) . W[:, h*128+d] + bias[h*128+d]
__global__ __launch_bounds__(128) void k2_out(const float* __restrict__ part,
                                              const float* __restrict__ W,
                                              const float* __restrict__ bias,
                                              float* __restrict__ out)
{
    const int b = blockIdx.x;
    const int h = blockIdx.y;
    const int tid = threadIdx.x;     // 0..127
    const float* pb = part + (size_t)b * NSLICE * PSTRIDE;

    __shared__ float Sn[NC];
    __shared__ float sL;
    if (tid == 0) {
        float L = 0.f;
        #pragma unroll
        for (int c = 0; c < NSLICE; ++c) L += pb[(size_t)c * PSTRIDE + 4 + h];
        sL = L;
    }
    __syncthreads();
    {
        float s = 0.f;
        #pragma unroll 4
        for (int c = 0; c < NSLICE; ++c)
            s += pb[(size_t)c * PSTRIDE + 8 + h * NC + tid];
        Sn[tid] = s / sL;
    }
    __syncthreads();
    const int d = h * NC + tid;
    float acc = 0.f;
    #pragma unroll 4
    for (int k = 0; k < NC; ++k) acc += Sn[k] * W[(size_t)k * HC + d];
    out[(size_t)b * HC + d] = acc + bias[d];
}

extern "C" void kernel_launch(void* const* d_in, const int* in_sizes, int n_in,
                              void* d_out, int out_size, void* d_ws, size_t ws_size,
                              hipStream_t stream)
{
    const float* V    = (const float*)d_in[0];
    const int*   gsz  = (const int*)d_in[1];
    const float* W    = (const float*)d_in[2];
    const float* bias = (const float*)d_in[3];
    const float* tune = (const float*)d_in[4];
    float* out  = (float*)d_out;
    float* wtbt = (float*)d_ws;            // 520 floats (516 used)
    float* part = wtbt + PSTRIDE;          // NB*NSLICE*PSTRIDE floats (~2.1 MB)

    hipLaunchKernelGGL(k0_wt, dim3(NC + 1), dim3(128), 0, stream, W, bias, tune, wtbt);
    hipLaunchKernelGGL(k1_part, dim3(NSLICE, NB), dim3(256), 0, stream, V, gsz, wtbt, part);
    hipLaunchKernelGGL(k2_out, dim3(NB, NH), dim3(128), 0, stream, part, W, bias, out);
}

// Round 23
// 47.298 us; speedup vs baseline: 1.0925x; 1.0060x over previous
//
#include <hip/hip_runtime.h>

#define NB 64
#define NN 4096
#define NC 128
#define NH 4
#define HC (NH * NC)        // 512
#define PSTRIDE (8 + HC)    // 520 floats per partial
#define TROWS 64            // rows per tile (32 KB)
#define NBLK 1024           // k1 grid = exactly the machine's block slots
#define MAXT 4096           // max tiles (all gs = 4096)
#define LRELU 0.2f

// ws float-index layout: [0,520) wtbt | [520,585) starts (65 ints) |
// [585, 585+4096) tile table (ints: b<<16|win) | partials from 4681
#define WS_STARTS 520
#define WS_TABLE  585
#define WS_PART   (WS_TABLE + MAXT)

// ---------------- k0: wt/bt precompute + compacted VALID-tile table build.
// grid NC+2: blocks 0..127 = W rows; block 128 = bias; block 129 = tile table.
__global__ __launch_bounds__(128) void k0_wt(const float* __restrict__ W,
                                             const float* __restrict__ bias,
                                             const float* __restrict__ tune,
                                             const int* __restrict__ gs,
                                             float* __restrict__ ws)
{
    const int bid = blockIdx.x;
    const int t = threadIdx.x;                       // 0..127
    if (bid <= NC) {
        const float* src = (bid < NC) ? (W + (size_t)bid * HC) : bias;
        float* dst = (bid < NC) ? (ws + bid * NH) : (ws + NC * NH);
        const float4 a = reinterpret_cast<const float4*>(src)[t];
        const float4 b = reinterpret_cast<const float4*>(tune)[t];
        float p = a.x * b.x + a.y * b.y + a.z * b.z + a.w * b.w;
        #pragma unroll
        for (int off = 16; off; off >>= 1) p += __shfl_xor(p, off, 32);
        if ((t & 31) == 0) dst[t >> 5] = p;          // group t>>5 == head h
    } else {
        // ---- tile table: tiles of 64 rows, only valid ones, prefix-ordered
        __shared__ int ntile[NB], st[NB + 1];
        if (t < NB) ntile[t] = (gs[t] + TROWS - 1) / TROWS;
        __syncthreads();
        if (t == 0) {
            int acc = 0;
            for (int b2 = 0; b2 < NB; ++b2) { st[b2] = acc; acc += ntile[b2]; }
            st[NB] = acc;
        }
        __syncthreads();
        int* wsI = reinterpret_cast<int*>(ws);
        if (t < NB + 1) wsI[WS_STARTS + t] = st[t];
        if (t < NB) {
            const int s0 = st[t], n0 = ntile[t];
            for (int w = 0; w < n0; ++w) wsI[WS_TABLE + s0 + w] = (t << 16) | w;
        }
    }
}

// ---------------- k1: 1024 blocks grid-stride over the compacted tile table.
// Every tile = identical work (stage 32KB -> compute -> per-tile partial), so
// per-CU load is uniform (~8 tiles) regardless of graph-size skew. Tile body is
// r15's proven stage+compute verbatim.
__global__ __launch_bounds__(256, 4) void k1_part(const float* __restrict__ V,
                                                  const int* __restrict__ gs,
                                                  float* __restrict__ ws)
{
    __shared__ float smem[8192];                     // 32 KB, unioned per-phase
    float (*Vt)[NC] = reinterpret_cast<float(*)[NC]>(smem);          // [64][128]
    float (*Sall)[NH][132] = reinterpret_cast<float(*)[NH][132]>(smem); // [8][4][132]
    float* llds = smem + 8 * NH * 132;               // 32 floats

    const int* wsI = reinterpret_cast<const int*>(ws);
    const int T = wsI[WS_STARTS + NB];
    const int* tab = wsI + WS_TABLE;
    float* part = ws + WS_PART;
    const float* wtbt = ws;

    const int tid = threadIdx.x;
    const int hw = tid >> 5;          // half-wave 0..7
    const int lane = tid & 31;
    const int h = lane >> 3;          // head 0..3
    const int j = lane & 7;           // feature-group (features 16j..16j+15)

    float wtk[16];
    #pragma unroll
    for (int u = 0; u < 16; ++u) wtk[u] = wtbt[(16 * j + u) * NH + h];
    const float bt = wtbt[HC + h];

    const float4* Vg4 = reinterpret_cast<const float4*>(V);

    for (int jt = blockIdx.x; jt < T; jt += NBLK) {
        const int ent = tab[jt];
        const int b = ent >> 16;
        const int tbase = (ent & 0xffff) * TROWS;
        const int gsz = gs[b];
        int tend = tbase + TROWS;
        if (tend > gsz) tend = gsz;
        const size_t gbase = (size_t)b * NN;

        // ---- stage: 2048 float4; thread t does idx = t + 256k (8 indep loads)
        float4 r[8];
        #pragma unroll
        for (int k = 0; k < 8; ++k) {
            const int idx = tid + (k << 8);
            const int gr = tbase + (idx >> 5);
            const int src_row = (gr < tend) ? gr : tbase;    // clamp (masked later)
            r[k] = Vg4[(gbase + src_row) * 32 + (idx & 31)];
        }
        #pragma unroll
        for (int k = 0; k < 8; ++k) {
            const int idx = tid + (k << 8);
            reinterpret_cast<float4*>(smem)[idx] = r[k];
        }
        __syncthreads();

        // ---- compute: half-wave hw handles rows hw*8 .. hw*8+7 from LDS
        float l = 0.f;
        float S[16] = {};
        #pragma unroll 2
        for (int rr = 0; rr < 8; ++rr) {
            const int row = (hw << 3) + rr;
            const bool valid = (tbase + row < tend);
            const float4* vr = reinterpret_cast<const float4*>(&Vt[row][j * 16]);
            const float4 A0 = vr[0];
            const float4 A1 = vr[1];
            const float4 A2 = vr[2];
            const float4 A3 = vr[3];
            float a0 = A0.x * wtk[0]  + A0.y * wtk[1]  + A0.z * wtk[2]  + A0.w * wtk[3];
            float a1 = A1.x * wtk[4]  + A1.y * wtk[5]  + A1.z * wtk[6]  + A1.w * wtk[7];
            float a2 = A2.x * wtk[8]  + A2.y * wtk[9]  + A2.z * wtk[10] + A2.w * wtk[11];
            float a3 = A3.x * wtk[12] + A3.y * wtk[13] + A3.z * wtk[14] + A3.w * wtk[15];
            float lg = (a0 + a1) + (a2 + a3);
            lg += __shfl_xor(lg, 1, 32);
            lg += __shfl_xor(lg, 2, 32);
            lg += __shfl_xor(lg, 4, 32);   // 8-lane head group holds full logit
            float x = lg + bt;
            x = (x >= 0.f) ? x : LRELU * x;           // leaky_relu
            float p = __expf(x);                      // no max subtraction
            p = valid ? p : 0.f;
            l += p;
            S[0]  += p * A0.x;  S[1]  += p * A0.y;  S[2]  += p * A0.z;  S[3]  += p * A0.w;
            S[4]  += p * A1.x;  S[5]  += p * A1.y;  S[6]  += p * A1.z;  S[7]  += p * A1.w;
            S[8]  += p * A2.x;  S[9]  += p * A2.y;  S[10] += p * A2.z;  S[11] += p * A2.w;
            S[12] += p * A3.x;  S[13] += p * A3.y;  S[14] += p * A3.z;  S[15] += p * A3.w;
        }
        __syncthreads();                              // all Vt reads done

        // ---- combine across 8 half-waves (smem reused as Sall/llds)
        if (j == 0) llds[hw * NH + h] = l;
        #pragma unroll
        for (int t2 = 0; t2 < 4; ++t2) {
            float4 s4;
            s4.x = S[4 * t2]; s4.y = S[4 * t2 + 1]; s4.z = S[4 * t2 + 2]; s4.w = S[4 * t2 + 3];
            *reinterpret_cast<float4*>(&Sall[hw][h][16 * j + 4 * t2]) = s4;
        }
        __syncthreads();
        float* pb = part + (size_t)jt * PSTRIDE;
        if (tid < 4) {
            float L = 0.f;
            #pragma unroll
            for (int ww = 0; ww < 8; ++ww) L += llds[ww * NH + tid];
            pb[4 + tid] = L;
        }
        #pragma unroll
        for (int r2 = 0; r2 < 2; ++r2) {
            const int e = tid + r2 * 256;
            const int hh = e >> 7, k = e & 127;
            float s = 0.f;
            #pragma unroll
            for (int ww = 0; ww < 8; ++ww) s += Sall[ww][hh][k];
            pb[8 + e] = s;
        }
        __syncthreads();                              // partial done; smem reusable
    }
}

// ---------------- k2: block (b, h): merge graph b's tiles [st[b], st[b+1]),
// wave-parallel L reduce, then out[b, h*128+d] = (S/L).W + bias
__global__ __launch_bounds__(128) void k2_out(const float* __restrict__ ws,
                                              const float* __restrict__ W,
                                              const float* __restrict__ bias,
                                              float* __restrict__ out)
{
    const int b = blockIdx.x;
    const int h = blockIdx.y;
    const int tid = threadIdx.x;     // 0..127
    const int* wsI = reinterpret_cast<const int*>(ws);
    const int s0 = wsI[WS_STARTS + b];
    const int n0 = wsI[WS_STARTS + b + 1] - s0;
    const float* pb = ws + WS_PART + (size_t)s0 * PSTRIDE;

    __shared__ float Sn[NC];
    __shared__ float sL;
    if (tid < 64) {                   // one wave: parallel L loads + shfl reduce
        float lv = (tid < n0) ? pb[(size_t)tid * PSTRIDE + 4 + h] : 0.f;
        #pragma unroll
        for (int off = 32; off; off >>= 1) lv += __shfl_down(lv, off, 64);
        if (tid == 0) sL = lv;
    }
    __syncthreads();
    {
        float s = 0.f;
        for (int c = 0; c < n0; ++c)
            s += pb[(size_t)c * PSTRIDE + 8 + h * NC + tid];
        Sn[tid] = s / sL;
    }
    __syncthreads();
    const int d = h * NC + tid;
    float acc = 0.f;
    #pragma unroll 4
    for (int k = 0; k < NC; ++k) acc += Sn[k] * W[(size_t)k * HC + d];
    out[(size_t)b * HC + d] = acc + bias[d];
}

extern "C" void kernel_launch(void* const* d_in, const int* in_sizes, int n_in,
                              void* d_out, int out_size, void* d_ws, size_t ws_size,
                              hipStream_t stream)
{
    const float* V    = (const float*)d_in[0];
    const int*   gsz  = (const int*)d_in[1];
    const float* W    = (const float*)d_in[2];
    const float* bias = (const float*)d_in[3];
    const float* tune = (const float*)d_in[4];
    float* out = (float*)d_out;
    float* ws  = (float*)d_ws;

    hipLaunchKernelGGL(k0_wt, dim3(NC + 2), dim3(128), 0, stream, W, bias, tune, gsz, ws);
    hipLaunchKernelGGL(k1_part, dim3(NBLK), dim3(256), 0, stream, V, gsz, ws);
    hipLaunchKernelGGL(k2_out, dim3(NB, NH), dim3(128), 0, stream, ws, W, bias, out);
}